// Round 17
// baseline (273.166 us; speedup 1.0000x reference)
//
#include <hip/hip_runtime.h>
#include <hip/hip_bf16.h>
#include <stdint.h>

typedef unsigned short u16;
typedef __bf16 bf16_t;
typedef bf16_t bf16x8 __attribute__((ext_vector_type(8)));
typedef float f32x4 __attribute__((ext_vector_type(4)));

#define DEV static __device__ __forceinline__

// Q pack scale: 0.125 * log2(e) -> softmax runs in exp2 domain (bias is {0,-3e38}: domain-free)
#define QSCALE 0.18033688011112042f

DEV u16 f2b(float f) {
    __hip_bfloat16 h = __float2bfloat16(f);
    return __builtin_bit_cast(u16, h);
}

DEV bf16x8 ld_frag(const u16* p) {
    uint4 u = *reinterpret_cast<const uint4*>(p);
    return __builtin_bit_cast(bf16x8, u);
}

// exact-GELU via tanh identity (max abs err ~3e-4; margin is 0.07)
DEV float gelu(float v) {
    float y = 0.79788456080286536f * (v + 0.044715f * v * v * v);
    float e = __expf(-2.f * fabsf(y));
    float th = (1.f - e) / (1.f + e);
    th = copysignf(th, y);
    return 0.5f * v * (1.f + th);
}

DEV void gl_lds16(const u16* g, u16* l) {
    __builtin_amdgcn_global_load_lds(
        (const __attribute__((address_space(1))) void*)(uintptr_t)g,
        (__attribute__((address_space(3))) void*)(unsigned int)(uintptr_t)l,
        16, 0, 0);
}

// ---------- fused prologue: transpose-in (4096 blocks) + w-conv (4096) + bias copies (16) ----------
struct ConvEnt { const float* s; u16* d; int n; };
struct CpyEnt { const float* s; float* d; };
struct PreArgs {
    const float* LL; const float* LH;
    float* llf; u16* llb; float* lhf; u16* lhb;
    ConvEnt ce[16];
    CpyEnt pe[8];
};

__global__ __launch_bounds__(256) void k_pre(PreArgs a) {
    __shared__ float tb[32][33];
    const int bid = blockIdx.x, t = threadIdx.x;
    if (bid < 4096) {
        const int z = bid >> 9, gy = (bid >> 5) & 15, gx = bid & 31;
        const int b = z & 3;
        const float* in = (z < 4) ? a.LL : a.LH;
        float* of = (z < 4) ? a.llf : a.lhf;
        u16* ob = (z < 4) ? a.llb : a.lhb;
        const int l0 = gx * 32, d0 = gy * 32;
        const int tx = t & 31, ty = t >> 5;
#pragma unroll
        for (int j = 0; j < 4; ++j) {
            int d = d0 + ty + j * 8;
            tb[ty + j * 8][tx] = in[((size_t)b * 512 + d) * 1024 + l0 + tx];
        }
        __syncthreads();
#pragma unroll
        for (int j = 0; j < 4; ++j) {
            int l = l0 + ty + j * 8;
            float v = tb[tx][ty + j * 8];
            size_t o = ((size_t)b * 1024 + l) * 512 + d0 + tx;
            of[o] = v;
            ob[o] = f2b(v);
        }
    } else if (bid < 8192) {
        const int cb = bid - 4096;
        const ConvEnt en = a.ce[cb >> 8];
        for (int i = ((cb & 255) * 256 + t) * 4; i < en.n; i += 256 * 256 * 4) {
            const float4 f = *reinterpret_cast<const float4*>(en.s + i);
            unsigned r0 = (unsigned)f2b(f.x) | ((unsigned)f2b(f.y) << 16);
            unsigned r1 = (unsigned)f2b(f.z) | ((unsigned)f2b(f.w) << 16);
            uint2 rr; rr.x = r0; rr.y = r1;
            *reinterpret_cast<uint2*>(en.d + i) = rr;
        }
    } else {
        const int cb = bid - 8192;
        const CpyEnt en = a.pe[cb >> 1];
        const int i = (cb & 1) * 256 + t;
        en.d[i] = en.s[i];
    }
}

// ---------- merged transpose out ----------
__global__ __launch_bounds__(256) void k_tout(const float* __restrict__ y0, const float* __restrict__ y1,
                                              float* __restrict__ out) {
    __shared__ float tb[32][33];
    int z = blockIdx.z, b = z & 3;
    const float* in = (z < 4) ? y0 : y1;
    float* o = out + ((z < 4) ? 0 : (size_t)4096 * 512);
    int l0 = blockIdx.x * 32, d0 = blockIdx.y * 32;
    int tx = threadIdx.x, ty = threadIdx.y;
#pragma unroll
    for (int j = 0; j < 4; ++j) {
        int l = l0 + ty + j * 8;
        tb[ty + j * 8][tx] = in[((size_t)b * 1024 + l) * 512 + d0 + tx];
    }
    __syncthreads();
#pragma unroll
    for (int j = 0; j < 4; ++j) {
        int d = d0 + ty + j * 8;
        o[((size_t)b * 512 + d) * 1024 + l0 + tx] = tb[tx][ty + j * 8];
    }
}

// ---------- energy mask ----------
__global__ __launch_bounds__(256) void k_mask(const float* __restrict__ lh_s,
                                              const float* __restrict__ raw_tau,
                                              float* __restrict__ kbias) {
    int row = blockIdx.x * 4 + (threadIdx.x >> 6);
    int lane = threadIdx.x & 63;
    const float* p = lh_s + (size_t)row * 512 + lane * 8;
    float s = 0.f;
#pragma unroll
    for (int j = 0; j < 8; ++j) s += fabsf(p[j]);
#pragma unroll
    for (int m = 32; m >= 1; m >>= 1) s += __shfl_xor(s, m, 64);
    float tau = 1.f / (1.f + expf(-raw_tau[0]));
    if (lane == 0) kbias[row] = (s * (1.f / 512.f) > tau) ? 0.f : -3.0e38f;
}

// ---------- LayerNorm ----------
__global__ __launch_bounds__(256) void k_ln(const float* __restrict__ a, const float* __restrict__ b,
                                            const float* __restrict__ c, const float* __restrict__ w,
                                            const float* __restrict__ bi,
                                            float* __restrict__ of, u16* __restrict__ ob) {
    int row = blockIdx.x * 4 + (threadIdx.x >> 6);
    int lane = threadIdx.x & 63;
    size_t base = (size_t)row * 512 + lane * 8;
    float x[8];
#pragma unroll
    for (int j = 0; j < 8; ++j) {
        float v = a[base + j] + b[base + j];
        if (c) v += c[base + j];
        x[j] = v;
    }
    float s = 0.f, s2 = 0.f;
#pragma unroll
    for (int j = 0; j < 8; ++j) { s += x[j]; s2 += x[j] * x[j]; }
#pragma unroll
    for (int m = 32; m >= 1; m >>= 1) { s += __shfl_xor(s, m, 64); s2 += __shfl_xor(s2, m, 64); }
    float mean = s * (1.f / 512.f);
    float var = s2 * (1.f / 512.f) - mean * mean;
    float rs = rsqrtf(var + 1e-5f);
#pragma unroll
    for (int j = 0; j < 8; ++j) {
        float y = (x[j] - mean) * rs * w[lane * 8 + j] + bi[lane * 8 + j];
        of[base + j] = y;
        ob[base + j] = f2b(y);
    }
}

// ---------- paired bf16 MFMA GEMM (blockIdx.y selects descriptor) ----------
struct GP {
    const u16* A; const u16* W; const float* bias; const float* res;
    float* Cf; u16* Cb; u16* Qp; u16* Kp; u16* Vt;
    int N, K, kB, vB, nwg;
};

template <int BM, int BN, int GELU_ACT, int PACK>
__global__ __launch_bounds__(256) void k_gemm(GP p0, GP p1, int M) {
    constexpr int BK = 64;
    __shared__ alignas(16) u16 Al[2][BM * BK];
    __shared__ alignas(16) u16 Wl[2][BN * BK];
    GP g = (blockIdx.y == 0) ? p0 : p1;
    const int orig = blockIdx.x;
    if (orig >= g.nwg) return;
    int bid;
    {
        const int xcd = orig & 7, lin = orig >> 3;
        const int q = g.nwg >> 3, r = g.nwg & 7;
        bid = (xcd < r ? xcd * (q + 1) : r * (q + 1) + (xcd - r) * q) + lin;
    }
    const int K = g.K, N = g.N;
    const int nny = N / BN;
    const int m0 = (bid / nny) * BM, n0 = (bid % nny) * BN;

    const int t = threadIdx.x, w = t >> 6, l = t & 63;
    constexpr int FM = BM / 32, FN = BN / 32;
    const int wr = w >> 1, wc = w & 1;
    const int lq = l & 15, lg = l >> 4;
    f32x4 acc[FM][FN] = {};

    const int srow = l >> 3, schunk = l & 7;
    auto stage = [&](int kcol, int buf) {
#pragma unroll
        for (int i = 0; i < BM / 32; ++i) {
            const int row = i * 32 + w * 8 + srow;
            gl_lds16(g.A + (size_t)(m0 + row) * K + kcol + ((schunk ^ (row & 7)) * 8),
                     &Al[buf][(i * 32 + w * 8) * BK]);
        }
#pragma unroll
        for (int i = 0; i < BN / 32; ++i) {
            const int row = i * 32 + w * 8 + srow;
            gl_lds16(g.W + (size_t)(n0 + row) * K + kcol + ((schunk ^ (row & 7)) * 8),
                     &Wl[buf][(i * 32 + w * 8) * BK]);
        }
    };

    stage(0, 0);
    const int KT = K / BK;
    for (int kt = 0; kt < KT; ++kt) {
        const int cur = kt & 1;
        __syncthreads();
        if (kt + 1 < KT) stage((kt + 1) * BK, cur ^ 1);
#pragma unroll
        for (int s = 0; s < 2; ++s) {
            bf16x8 af[FM], bw[FN];
#pragma unroll
            for (int i = 0; i < FM; ++i) {
                const int row = wr * (BM / 2) + i * 16 + lq;
                af[i] = ld_frag(&Al[cur][row * BK + (((s * 4 + lg) ^ (row & 7)) * 8)]);
            }
#pragma unroll
            for (int j = 0; j < FN; ++j) {
                const int row = wc * (BN / 2) + j * 16 + lq;
                bw[j] = ld_frag(&Wl[cur][row * BK + (((s * 4 + lg) ^ (row & 7)) * 8)]);
            }
#pragma unroll
            for (int i = 0; i < FM; ++i)
#pragma unroll
                for (int j = 0; j < FN; ++j)
                    acc[i][j] = __builtin_amdgcn_mfma_f32_16x16x32_bf16(af[i], bw[j], acc[i][j], 0, 0, 0);
        }
    }

    if (PACK && n0 >= g.vB) {
        u16* T = (u16*)Al;
        constexpr int CH = BM / 8, CMASK = CH - 1, SH = (CH == 16) ? 4 : 3;
        __syncthreads();
#pragma unroll
        for (int i = 0; i < FM; ++i) {
#pragma unroll
            for (int j = 0; j < FN; ++j) {
                const int ni = wc * (BN / 2) + j * 16 + lq;
                const float bn = g.bias[n0 + ni];
#pragma unroll
                for (int r2 = 0; r2 < 4; ++r2) {
                    const int mi = wr * (BM / 2) + i * 16 + lg * 4 + r2;
                    T[ni * BM + (((mi >> 3) ^ (ni & CMASK)) * 8) + (mi & 7)] = f2b(acc[i][j][r2] + bn);
                }
            }
        }
        __syncthreads();
        const int bb = m0 >> 10, mloc = m0 & 1023;
        const int mc = t & CMASK, nib = t >> SH;
        constexpr int RPP = 256 / CH;
#pragma unroll
        for (int p2 = 0; p2 < BN / RPP; ++p2) {
            const int ni = nib + p2 * RPP;
            uint4 u = *reinterpret_cast<const uint4*>(&T[ni * BM + ((mc ^ (ni & CMASK)) * 8)]);
            const int d = n0 - g.vB + ni;
            *reinterpret_cast<uint4*>(
                &g.Vt[((size_t)(bb * 8 + (d >> 6)) * 64 + (d & 63)) * 1024 + mloc + mc * 8]) = u;
        }
        return;
    }

#pragma unroll
    for (int i = 0; i < FM; ++i) {
#pragma unroll
        for (int j = 0; j < FN; ++j) {
            const int n = n0 + wc * (BN / 2) + j * 16 + lq;
            const float bn = g.bias[n];
#pragma unroll
            for (int r2 = 0; r2 < 4; ++r2) {
                const int m = m0 + wr * (BM / 2) + i * 16 + lg * 4 + r2;
                float v = acc[i][j][r2] + bn;
                if (GELU_ACT) v = gelu(v);
                if (PACK) {
                    const int bb = m >> 10, ll_ = m & 1023;
                    if (n >= g.kB) {
                        const int d = n - g.kB;
                        g.Kp[((size_t)(bb * 8 + (d >> 6)) * 1024 + ll_) * 64 + (d & 63)] = f2b(v);
                    } else {
                        g.Qp[((size_t)(bb * 8 + (n >> 6)) * 1024 + ll_) * 64 + (n & 63)] = f2b(v * QSCALE);
                    }
                } else {
                    size_t o = (size_t)m * N + n;
                    if (g.res) v += g.res[o];
                    if (g.Cf) g.Cf[o] = v;
                    if (g.Cb) g.Cb[o] = f2b(v);
                }
            }
        }
    }
}

// ---------- flash attention: QBLK=128, swapped QK^T (S^T), packed b64 P-writes, exp2 softmax ----------
__global__ __launch_bounds__(256) void k_attn(const u16* __restrict__ Qp, const u16* __restrict__ Kp,
                                              const u16* __restrict__ Vtp, u16* __restrict__ O,
                                              const float* __restrict__ kbias, int nwg) {
    constexpr int L = 1024;
    __shared__ alignas(16) u16 Kl[2][64 * 64];
    __shared__ alignas(16) u16 Vl[2][64 * 64];
    __shared__ alignas(16) u16 Pl[128 * 64];
    const int t = threadIdx.x, w = t >> 6, l = t & 63;
    const int bid = ((int)blockIdx.x & 7) * (nwg >> 3) + ((int)blockIdx.x >> 3);
    const int bh = bid >> 3, q0 = (bid & 7) * 128;
    const int bz = bh >> 3, h = bh & 7;
    const int lq = l & 15, lg = l >> 4;
    const float* kb = (kbias != nullptr && bz >= 4) ? (kbias + (size_t)(bz - 4) * L) : nullptr;

    bf16x8 qa[2][2];
#pragma unroll
    for (int i = 0; i < 2; ++i) {
        const u16* qp = Qp + ((size_t)bh * L + q0 + w * 32 + i * 16 + lq) * 64 + lg * 8;
        qa[i][0] = ld_frag(qp);
        qa[i][1] = ld_frag(qp + 32);
    }

    const int r0 = w * 16 + (l >> 3), r1 = r0 + 8, c = l & 7;
    const u16* Ksrc0 = Kp + (size_t)bh * L * 64 + (size_t)r0 * 64 + ((c ^ (r0 & 7)) * 8);
    const u16* Ksrc1 = Kp + (size_t)bh * L * 64 + (size_t)r1 * 64 + ((c ^ (r1 & 7)) * 8);
    const u16* Vsrc0 = Vtp + (size_t)bh * 64 * L + (size_t)r0 * L + ((c ^ (r0 & 7)) * 8);
    const u16* Vsrc1 = Vtp + (size_t)bh * 64 * L + (size_t)r1 * L + ((c ^ (r1 & 7)) * 8);

    auto stage = [&](int k0, int buf) {
        gl_lds16(Ksrc0 + (size_t)k0 * 64, &Kl[buf][(w * 16) * 64]);
        gl_lds16(Ksrc1 + (size_t)k0 * 64, &Kl[buf][(w * 16 + 8) * 64]);
        gl_lds16(Vsrc0 + k0, &Vl[buf][(w * 16) * 64]);
        gl_lds16(Vsrc1 + k0, &Vl[buf][(w * 16 + 8) * 64]);
    };

    int addrA[4][2];
#pragma unroll
    for (int f = 0; f < 4; ++f) {
        int row = f * 16 + lq;
#pragma unroll
        for (int s = 0; s < 2; ++s) addrA[f][s] = row * 64 + (((s * 4 + lg) ^ (row & 7)) * 8);
    }
    int pwr[2][4], paddr[2][2];
#pragma unroll
    for (int i = 0; i < 2; ++i) {
        const int q = w * 32 + i * 16 + lq;
#pragma unroll
        for (int f = 0; f < 4; ++f) {
            const int chunk = f * 2 + (lg >> 1);
            pwr[i][f] = q * 64 + ((chunk ^ (lq & 7)) * 8) + (lg & 1) * 4;
        }
#pragma unroll
        for (int s = 0; s < 2; ++s) paddr[i][s] = q * 64 + (((s * 4 + lg) ^ (lq & 7)) * 8);
    }

    f32x4 oacc[2][4] = {};
    float lsum[2] = {0.f, 0.f};

    stage(0, 0);
    for (int kt = 0; kt < 16; ++kt) {
        const int cur = kt & 1;
        __syncthreads();
        if (kt + 1 < 16) stage((kt + 1) * 64, cur ^ 1);

        f32x4 sc[2][4];
#pragma unroll
        for (int f = 0; f < 4; ++f) {
            bf16x8 k0 = ld_frag(&Kl[cur][addrA[f][0]]);
            bf16x8 k1 = ld_frag(&Kl[cur][addrA[f][1]]);
#pragma unroll
            for (int i = 0; i < 2; ++i) {
                f32x4 a = {};
                a = __builtin_amdgcn_mfma_f32_16x16x32_bf16(k0, qa[i][0], a, 0, 0, 0);
                a = __builtin_amdgcn_mfma_f32_16x16x32_bf16(k1, qa[i][1], a, 0, 0, 0);
                sc[i][f] = a;
            }
        }
#pragma unroll
        for (int f = 0; f < 4; ++f) {
            float4 bv4;
            if (kb) bv4 = *reinterpret_cast<const float4*>(kb + kt * 64 + f * 16 + lg * 4);
            else { bv4.x = 0.f; bv4.y = 0.f; bv4.z = 0.f; bv4.w = 0.f; }
#pragma unroll
            for (int i = 0; i < 2; ++i) {
                float p0 = exp2f(sc[i][f][0] + bv4.x);
                float p1 = exp2f(sc[i][f][1] + bv4.y);
                float p2 = exp2f(sc[i][f][2] + bv4.z);
                float p3 = exp2f(sc[i][f][3] + bv4.w);
                lsum[i] += (p0 + p1) + (p2 + p3);
                uint2 pk;
                pk.x = (unsigned)f2b(p0) | ((unsigned)f2b(p1) << 16);
                pk.y = (unsigned)f2b(p2) | ((unsigned)f2b(p3) << 16);
                *reinterpret_cast<uint2*>(&Pl[pwr[i][f]]) = pk;
            }
        }
        bf16x8 pa[2][2];
#pragma unroll
        for (int i = 0; i < 2; ++i) {
            pa[i][0] = ld_frag(&Pl[paddr[i][0]]);
            pa[i][1] = ld_frag(&Pl[paddr[i][1]]);
        }
#pragma unroll
        for (int db = 0; db < 4; ++db) {
            bf16x8 v0 = ld_frag(&Vl[cur][addrA[db][0]]);
            bf16x8 v1 = ld_frag(&Vl[cur][addrA[db][1]]);
#pragma unroll
            for (int i = 0; i < 2; ++i) {
                oacc[i][db] = __builtin_amdgcn_mfma_f32_16x16x32_bf16(pa[i][0], v0, oacc[i][db], 0, 0, 0);
                oacc[i][db] = __builtin_amdgcn_mfma_f32_16x16x32_bf16(pa[i][1], v1, oacc[i][db], 0, 0, 0);
            }
        }
    }
#pragma unroll
    for (int i = 0; i < 2; ++i) {
        float v = lsum[i];
        v += __shfl_xor(v, 16, 64);
        v += __shfl_xor(v, 32, 64);
        lsum[i] = v;
    }
#pragma unroll
    for (int i = 0; i < 2; ++i) {
        float inv[4];
#pragma unroll
        for (int r = 0; r < 4; ++r) {
            float den = __shfl(lsum[i], lg * 4 + r, 64);
            inv[r] = (den > 0.f) ? 1.f / den : 0.f;
        }
#pragma unroll
        for (int db = 0; db < 4; ++db) {
#pragma unroll
            for (int r = 0; r < 4; ++r) {
                O[((size_t)bz * L + q0 + w * 32 + i * 16 + lg * 4 + r) * 512 + h * 64 + db * 16 + lq] =
                    f2b(oacc[i][db][r] * inv[r]);
            }
        }
    }
}

// ---------- host ----------
extern "C" void kernel_launch(void* const* d_in, const int* in_sizes, int n_in,
                              void* d_out, int out_size, void* d_ws, size_t ws_size,
                              hipStream_t stream) {
    const int M = 4096;
    const float* LL = (const float*)d_in[0];
    const float* LH = (const float*)d_in[1];
    const float* raw_tau = (const float*)d_in[2];
    auto F = [&](int i) { return (const float*)d_in[i]; };
    const int BIG = 1 << 28;

    char* p = (char*)d_ws;
    auto alloc = [&](size_t bytes) { void* r = (void*)p; p += (bytes + 255) & ~(size_t)255; return r; };
    const size_t MDf = (size_t)M * 512 * 4, MDb = (size_t)M * 512 * 2;
    float* ll_s_f = (float*)alloc(MDf);
    float* lh_s_f = (float*)alloc(MDf);
    u16* ll_s_b = (u16*)alloc(MDb);
    u16* lh_s_b = (u16*)alloc(MDb);
    u16* Qp = (u16*)alloc(2 * MDb);
    u16* Kp = (u16*)alloc(2 * MDb);
    u16* Vt = (u16*)alloc(2 * MDb);
    u16* Cxb = (u16*)alloc(2 * MDb);
    float* ll_o_f = (float*)alloc(MDf);
    u16* ll_o_b = (u16*)alloc(MDb);
    float* lh_o_f = (float*)alloc(MDf);
    u16* lh_o_b = (u16*)alloc(MDb);
    float* cr_o_f = (float*)alloc(MDf);
    float* ln_f_ll = (float*)alloc(MDf);
    float* ln_f_lh = (float*)alloc(MDf);
    u16* ln_b = (u16*)alloc(MDb);
    u16* hb = (u16*)alloc((size_t)M * 2048 * 2);
    float* yf_ll = (float*)alloc(MDf);
    float* yf_lh = (float*)alloc(MDf);
    float* kbias = (float*)alloc(4096 * 4);
    float* bqkv_ll = (float*)alloc(1536 * 4);
    float* bqkv_lh = (float*)alloc(1536 * 4);
    float* bkv_cr = (float*)alloc(1024 * 4);
    const size_t WDD = (size_t)262144;
    u16* wqkv_ll = (u16*)alloc(3 * WDD * 2);
    u16* wqkv_lh = (u16*)alloc(3 * WDD * 2);
    u16* wkv_cr = (u16*)alloc(2 * WDD * 2);
    u16* wq_cr = (u16*)alloc(WDD * 2);
    u16* wo_ll = (u16*)alloc(WDD * 2);
    u16* wo_lh = (u16*)alloc(WDD * 2);
    u16* wo_cr = (u16*)alloc(WDD * 2);
    u16* wm[4];
    for (int i = 0; i < 4; ++i) wm[i] = (u16*)alloc((size_t)1048576 * 2);

    const size_t SET = (size_t)4 * 8 * 1024 * 64;

    PreArgs pa;
    pa.LL = LL; pa.LH = LH;
    pa.llf = ll_s_f; pa.llb = ll_s_b; pa.lhf = lh_s_f; pa.lhb = lh_s_b;
    pa.ce[0] = {F(3), wqkv_ll, (int)WDD};
    pa.ce[1] = {F(5), wqkv_ll + WDD, (int)WDD};
    pa.ce[2] = {F(7), wqkv_ll + 2 * WDD, (int)WDD};
    pa.ce[3] = {F(11), wqkv_lh, (int)WDD};
    pa.ce[4] = {F(13), wqkv_lh + WDD, (int)WDD};
    pa.ce[5] = {F(15), wqkv_lh + 2 * WDD, (int)WDD};
    pa.ce[6] = {F(19), wq_cr, (int)WDD};
    pa.ce[7] = {F(21), wkv_cr, (int)WDD};
    pa.ce[8] = {F(23), wkv_cr + WDD, (int)WDD};
    pa.ce[9] = {F(9), wo_ll, (int)WDD};
    pa.ce[10] = {F(17), wo_lh, (int)WDD};
    pa.ce[11] = {F(25), wo_cr, (int)WDD};
    pa.ce[12] = {F(27), wm[0], 1048576};
    pa.ce[13] = {F(29), wm[1], 1048576};
    pa.ce[14] = {F(31), wm[2], 1048576};
    pa.ce[15] = {F(33), wm[3], 1048576};
    pa.pe[0] = {F(4), bqkv_ll};
    pa.pe[1] = {F(6), bqkv_ll + 512};
    pa.pe[2] = {F(8), bqkv_ll + 1024};
    pa.pe[3] = {F(12), bqkv_lh};
    pa.pe[4] = {F(14), bqkv_lh + 512};
    pa.pe[5] = {F(16), bqkv_lh + 1024};
    pa.pe[6] = {F(22), bkv_cr};
    pa.pe[7] = {F(24), bkv_cr + 512};
    k_pre<<<dim3(8208), 256, 0, stream>>>(pa);
    k_mask<<<dim3(1024), 256, 0, stream>>>(lh_s_f, raw_tau, kbias);

    auto gp = [&](const u16* A, const u16* W, const float* bias, int N, int K, int nwg) {
        GP g = {};
        g.A = A; g.W = W; g.bias = bias; g.N = N; g.K = K; g.nwg = nwg;
        g.kB = BIG; g.vB = BIG;
        return g;
    };

    // qkv pair (128x128, y selects ll/lh)
    {
        GP a = gp(ll_s_b, wqkv_ll, bqkv_ll, 1536, 512, 384);
        a.kB = 512; a.vB = 1024; a.Qp = Qp; a.Kp = Kp; a.Vt = Vt;
        GP b = gp(lh_s_b, wqkv_lh, bqkv_lh, 1536, 512, 384);
        b.kB = 512; b.vB = 1024; b.Qp = Qp + SET; b.Kp = Kp + SET; b.Vt = Vt + SET;
        k_gemm<128, 128, 0, 1><<<dim3(384, 2), 256, 0, stream>>>(a, b, M);
    }
    // merged self-attention (512 blocks)
    k_attn<<<dim3(512), 256, 0, stream>>>(Qp, Kp, Vt, Cxb, kbias, 512);
    // wo pair
    {
        GP a = gp(Cxb, wo_ll, F(10), 512, 512, 512);
        a.Cf = ll_o_f; a.Cb = ll_o_b;
        GP b = gp(Cxb + SET, wo_lh, F(18), 512, 512, 512);
        b.Cf = lh_o_f; b.Cb = lh_o_b;
        k_gemm<64, 64, 0, 0><<<dim3(512, 2), 256, 0, stream>>>(a, b, M);
    }
    k_ln<<<dim3(1024), 256, 0, stream>>>(lh_s_f, lh_o_f, nullptr, F(37), F(38), ln_f_lh, ln_b);
    // mlp_lh_up
    {
        GP a = gp(ln_b, wm[2], F(32), 2048, 512, 512);
        a.Cb = hb;
        k_gemm<128, 128, 1, 0><<<dim3(512, 1), 256, 0, stream>>>(a, a, M);
    }
    // crQ + crKV pair
    {
        GP a = gp(ll_o_b, wq_cr, F(20), 512, 512, 512);
        a.Qp = Qp;
        GP b = gp(lh_o_b, wkv_cr, bkv_cr, 1024, 512, 1024);
        b.kB = 0; b.vB = 512; b.Kp = Kp; b.Vt = Vt;
        k_gemm<64, 64, 0, 1><<<dim3(1024, 2), 256, 0, stream>>>(a, b, M);
    }
    // cross attention (256 blocks)
    k_attn<<<dim3(256), 256, 0, stream>>>(Qp, Kp, Vt, Cxb, nullptr, 256);
    // wo_cr + mlp_lh_down pair
    {
        GP a = gp(Cxb, wo_cr, F(26), 512, 512, 512);
        a.Cf = cr_o_f;
        GP b = gp(hb, wm[3], F(34), 512, 2048, 512);
        b.Cf = yf_lh; b.res = ln_f_lh;
        k_gemm<64, 64, 0, 0><<<dim3(512, 2), 256, 0, stream>>>(a, b, M);
    }
    k_ln<<<dim3(1024), 256, 0, stream>>>(ll_s_f, ll_o_f, cr_o_f, F(35), F(36), ln_f_ll, ln_b);
    // mlp_ll_up
    {
        GP a = gp(ln_b, wm[0], F(28), 2048, 512, 512);
        a.Cb = hb;
        k_gemm<128, 128, 1, 0><<<dim3(512, 1), 256, 0, stream>>>(a, a, M);
    }
    // mlp_ll_down
    {
        GP a = gp(hb, wm[1], F(30), 512, 2048, 512);
        a.Cf = yf_ll; a.res = ln_f_ll;
        k_gemm<64, 64, 0, 0><<<dim3(512, 1), 256, 0, stream>>>(a, a, M);
    }
    k_tout<<<dim3(32, 16, 8), dim3(32, 8), 0, stream>>>(yf_ll, yf_lh, (float*)d_out);
}

// Round 18
// 260.346 us; speedup vs baseline: 1.0492x; 1.0492x over previous
//
#include <hip/hip_runtime.h>
#include <hip/hip_bf16.h>
#include <stdint.h>

typedef unsigned short u16;
typedef __bf16 bf16_t;
typedef bf16_t bf16x8 __attribute__((ext_vector_type(8)));
typedef float f32x4 __attribute__((ext_vector_type(4)));

#define DEV static __device__ __forceinline__

DEV u16 f2b(float f) {
    __hip_bfloat16 h = __float2bfloat16(f);
    return __builtin_bit_cast(u16, h);
}

DEV bf16x8 ld_frag(const u16* p) {
    uint4 u = *reinterpret_cast<const uint4*>(p);
    return __builtin_bit_cast(bf16x8, u);
}

// exact-GELU via tanh identity (max abs err ~3e-4; margin is 0.07)
DEV float gelu(float v) {
    float y = 0.79788456080286536f * (v + 0.044715f * v * v * v);
    float e = __expf(-2.f * fabsf(y));
    float th = (1.f - e) / (1.f + e);
    th = copysignf(th, y);
    return 0.5f * v * (1.f + th);
}

DEV void gl_lds16(const u16* g, u16* l) {
    __builtin_amdgcn_global_load_lds(
        (const __attribute__((address_space(1))) void*)(uintptr_t)g,
        (__attribute__((address_space(3))) void*)(unsigned int)(uintptr_t)l,
        16, 0, 0);
}

// ---------- fused prologue: transpose-in (4096 blocks) + w-conv (4096) + bias copies (16) ----------
struct ConvEnt { const float* s; u16* d; int n; };
struct CpyEnt { const float* s; float* d; };
struct PreArgs {
    const float* LL; const float* LH;
    float* llf; u16* llb; float* lhf; u16* lhb;
    ConvEnt ce[16];
    CpyEnt pe[8];
};

__global__ __launch_bounds__(256) void k_pre(PreArgs a) {
    __shared__ float tb[32][33];
    const int bid = blockIdx.x, t = threadIdx.x;
    if (bid < 4096) {
        const int z = bid >> 9, gy = (bid >> 5) & 15, gx = bid & 31;
        const int b = z & 3;
        const float* in = (z < 4) ? a.LL : a.LH;
        float* of = (z < 4) ? a.llf : a.lhf;
        u16* ob = (z < 4) ? a.llb : a.lhb;
        const int l0 = gx * 32, d0 = gy * 32;
        const int tx = t & 31, ty = t >> 5;
#pragma unroll
        for (int j = 0; j < 4; ++j) {
            int d = d0 + ty + j * 8;
            tb[ty + j * 8][tx] = in[((size_t)b * 512 + d) * 1024 + l0 + tx];
        }
        __syncthreads();
#pragma unroll
        for (int j = 0; j < 4; ++j) {
            int l = l0 + ty + j * 8;
            float v = tb[tx][ty + j * 8];
            size_t o = ((size_t)b * 1024 + l) * 512 + d0 + tx;
            of[o] = v;
            ob[o] = f2b(v);
        }
    } else if (bid < 8192) {
        const int cb = bid - 4096;
        const ConvEnt en = a.ce[cb >> 8];
        for (int i = ((cb & 255) * 256 + t) * 4; i < en.n; i += 256 * 256 * 4) {
            const float4 f = *reinterpret_cast<const float4*>(en.s + i);
            unsigned r0 = (unsigned)f2b(f.x) | ((unsigned)f2b(f.y) << 16);
            unsigned r1 = (unsigned)f2b(f.z) | ((unsigned)f2b(f.w) << 16);
            uint2 rr; rr.x = r0; rr.y = r1;
            *reinterpret_cast<uint2*>(en.d + i) = rr;
        }
    } else {
        const int cb = bid - 8192;
        const CpyEnt en = a.pe[cb >> 1];
        const int i = (cb & 1) * 256 + t;
        en.d[i] = en.s[i];
    }
}

// ---------- merged transpose out ----------
__global__ __launch_bounds__(256) void k_tout(const float* __restrict__ y0, const float* __restrict__ y1,
                                              float* __restrict__ out) {
    __shared__ float tb[32][33];
    int z = blockIdx.z, b = z & 3;
    const float* in = (z < 4) ? y0 : y1;
    float* o = out + ((z < 4) ? 0 : (size_t)4096 * 512);
    int l0 = blockIdx.x * 32, d0 = blockIdx.y * 32;
    int tx = threadIdx.x, ty = threadIdx.y;
#pragma unroll
    for (int j = 0; j < 4; ++j) {
        int l = l0 + ty + j * 8;
        tb[ty + j * 8][tx] = in[((size_t)b * 1024 + l) * 512 + d0 + tx];
    }
    __syncthreads();
#pragma unroll
    for (int j = 0; j < 4; ++j) {
        int d = d0 + ty + j * 8;
        o[((size_t)b * 512 + d) * 1024 + l0 + tx] = tb[tx][ty + j * 8];
    }
}

// ---------- energy mask ----------
__global__ __launch_bounds__(256) void k_mask(const float* __restrict__ lh_s,
                                              const float* __restrict__ raw_tau,
                                              float* __restrict__ kbias) {
    int row = blockIdx.x * 4 + (threadIdx.x >> 6);
    int lane = threadIdx.x & 63;
    const float* p = lh_s + (size_t)row * 512 + lane * 8;
    float s = 0.f;
#pragma unroll
    for (int j = 0; j < 8; ++j) s += fabsf(p[j]);
#pragma unroll
    for (int m = 32; m >= 1; m >>= 1) s += __shfl_xor(s, m, 64);
    float tau = 1.f / (1.f + expf(-raw_tau[0]));
    if (lane == 0) kbias[row] = (s * (1.f / 512.f) > tau) ? 0.f : -3.0e38f;
}

// ---------- LayerNorm ----------
__global__ __launch_bounds__(256) void k_ln(const float* __restrict__ a, const float* __restrict__ b,
                                            const float* __restrict__ c, const float* __restrict__ w,
                                            const float* __restrict__ bi,
                                            float* __restrict__ of, u16* __restrict__ ob) {
    int row = blockIdx.x * 4 + (threadIdx.x >> 6);
    int lane = threadIdx.x & 63;
    size_t base = (size_t)row * 512 + lane * 8;
    float x[8];
#pragma unroll
    for (int j = 0; j < 8; ++j) {
        float v = a[base + j] + b[base + j];
        if (c) v += c[base + j];
        x[j] = v;
    }
    float s = 0.f, s2 = 0.f;
#pragma unroll
    for (int j = 0; j < 8; ++j) { s += x[j]; s2 += x[j] * x[j]; }
#pragma unroll
    for (int m = 32; m >= 1; m >>= 1) { s += __shfl_xor(s, m, 64); s2 += __shfl_xor(s2, m, 64); }
    float mean = s * (1.f / 512.f);
    float var = s2 * (1.f / 512.f) - mean * mean;
    float rs = rsqrtf(var + 1e-5f);
#pragma unroll
    for (int j = 0; j < 8; ++j) {
        float y = (x[j] - mean) * rs * w[lane * 8 + j] + bi[lane * 8 + j];
        of[base + j] = y;
        ob[base + j] = f2b(y);
    }
}

// ---------- paired bf16 MFMA GEMM (blockIdx.y selects descriptor) ----------
struct GP {
    const u16* A; const u16* W; const float* bias; const float* res;
    float* Cf; u16* Cb; u16* Qp; u16* Kp; u16* Vt;
    int N, K, kB, vB, nwg;
};

template <int BM, int BN, int GELU_ACT, int PACK>
__global__ __launch_bounds__(256) void k_gemm(GP p0, GP p1, int M) {
    constexpr int BK = 64;
    __shared__ alignas(16) u16 Al[2][BM * BK];
    __shared__ alignas(16) u16 Wl[2][BN * BK];
    GP g = (blockIdx.y == 0) ? p0 : p1;
    const int orig = blockIdx.x;
    if (orig >= g.nwg) return;
    int bid;
    {
        const int xcd = orig & 7, lin = orig >> 3;
        const int q = g.nwg >> 3, r = g.nwg & 7;
        bid = (xcd < r ? xcd * (q + 1) : r * (q + 1) + (xcd - r) * q) + lin;
    }
    const int K = g.K, N = g.N;
    const int nny = N / BN;
    const int m0 = (bid / nny) * BM, n0 = (bid % nny) * BN;

    const int t = threadIdx.x, w = t >> 6, l = t & 63;
    constexpr int FM = BM / 32, FN = BN / 32;
    const int wr = w >> 1, wc = w & 1;
    const int lq = l & 15, lg = l >> 4;
    f32x4 acc[FM][FN] = {};

    const int srow = l >> 3, schunk = l & 7;
    auto stage = [&](int kcol, int buf) {
#pragma unroll
        for (int i = 0; i < BM / 32; ++i) {
            const int row = i * 32 + w * 8 + srow;
            gl_lds16(g.A + (size_t)(m0 + row) * K + kcol + ((schunk ^ (row & 7)) * 8),
                     &Al[buf][(i * 32 + w * 8) * BK]);
        }
#pragma unroll
        for (int i = 0; i < BN / 32; ++i) {
            const int row = i * 32 + w * 8 + srow;
            gl_lds16(g.W + (size_t)(n0 + row) * K + kcol + ((schunk ^ (row & 7)) * 8),
                     &Wl[buf][(i * 32 + w * 8) * BK]);
        }
    };

    stage(0, 0);
    const int KT = K / BK;
    for (int kt = 0; kt < KT; ++kt) {
        const int cur = kt & 1;
        __syncthreads();
        if (kt + 1 < KT) stage((kt + 1) * BK, cur ^ 1);
#pragma unroll
        for (int s = 0; s < 2; ++s) {
            bf16x8 af[FM], bw[FN];
#pragma unroll
            for (int i = 0; i < FM; ++i) {
                const int row = wr * (BM / 2) + i * 16 + lq;
                af[i] = ld_frag(&Al[cur][row * BK + (((s * 4 + lg) ^ (row & 7)) * 8)]);
            }
#pragma unroll
            for (int j = 0; j < FN; ++j) {
                const int row = wc * (BN / 2) + j * 16 + lq;
                bw[j] = ld_frag(&Wl[cur][row * BK + (((s * 4 + lg) ^ (row & 7)) * 8)]);
            }
#pragma unroll
            for (int i = 0; i < FM; ++i)
#pragma unroll
                for (int j = 0; j < FN; ++j)
                    acc[i][j] = __builtin_amdgcn_mfma_f32_16x16x32_bf16(af[i], bw[j], acc[i][j], 0, 0, 0);
        }
    }

    if (PACK && n0 >= g.vB) {
        u16* T = (u16*)Al;
        constexpr int CH = BM / 8, CMASK = CH - 1, SH = (CH == 16) ? 4 : 3;
        __syncthreads();
#pragma unroll
        for (int i = 0; i < FM; ++i) {
#pragma unroll
            for (int j = 0; j < FN; ++j) {
                const int ni = wc * (BN / 2) + j * 16 + lq;
                const float bn = g.bias[n0 + ni];
#pragma unroll
                for (int r2 = 0; r2 < 4; ++r2) {
                    const int mi = wr * (BM / 2) + i * 16 + lg * 4 + r2;
                    T[ni * BM + (((mi >> 3) ^ (ni & CMASK)) * 8) + (mi & 7)] = f2b(acc[i][j][r2] + bn);
                }
            }
        }
        __syncthreads();
        const int bb = m0 >> 10, mloc = m0 & 1023;
        const int mc = t & CMASK, nib = t >> SH;
        constexpr int RPP = 256 / CH;
#pragma unroll
        for (int p2 = 0; p2 < BN / RPP; ++p2) {
            const int ni = nib + p2 * RPP;
            uint4 u = *reinterpret_cast<const uint4*>(&T[ni * BM + ((mc ^ (ni & CMASK)) * 8)]);
            const int d = n0 - g.vB + ni;
            *reinterpret_cast<uint4*>(
                &g.Vt[((size_t)(bb * 8 + (d >> 6)) * 64 + (d & 63)) * 1024 + mloc + mc * 8]) = u;
        }
        return;
    }

#pragma unroll
    for (int i = 0; i < FM; ++i) {
#pragma unroll
        for (int j = 0; j < FN; ++j) {
            const int n = n0 + wc * (BN / 2) + j * 16 + lq;
            const float bn = g.bias[n];
#pragma unroll
            for (int r2 = 0; r2 < 4; ++r2) {
                const int m = m0 + wr * (BM / 2) + i * 16 + lg * 4 + r2;
                float v = acc[i][j][r2] + bn;
                if (GELU_ACT) v = gelu(v);
                if (PACK) {
                    const int bb = m >> 10, ll_ = m & 1023;
                    if (n >= g.kB) {
                        const int d = n - g.kB;
                        g.Kp[((size_t)(bb * 8 + (d >> 6)) * 1024 + ll_) * 64 + (d & 63)] = f2b(v);
                    } else {
                        g.Qp[((size_t)(bb * 8 + (n >> 6)) * 1024 + ll_) * 64 + (n & 63)] = f2b(v * 0.125f);
                    }
                } else {
                    size_t o = (size_t)m * N + n;
                    if (g.res) v += g.res[o];
                    if (g.Cf) g.Cf[o] = v;
                    if (g.Cb) g.Cb[o] = f2b(v);
                }
            }
        }
    }
}

// ---------- flash attention: QBLK=128, swapped QK^T (S^T), packed b64 P-writes ----------
// mfma(K,Q) -> lane holds P[q=lq][key=f*16+lg*4+r] : 4 k-contiguous values -> 1 ds_write_b64.
__global__ __launch_bounds__(256) void k_attn(const u16* __restrict__ Qp, const u16* __restrict__ Kp,
                                              const u16* __restrict__ Vtp, u16* __restrict__ O,
                                              const float* __restrict__ kbias, int nwg) {
    constexpr int L = 1024;
    __shared__ alignas(16) u16 Kl[2][64 * 64];
    __shared__ alignas(16) u16 Vl[2][64 * 64];
    __shared__ alignas(16) u16 Pl[128 * 64];
    const int t = threadIdx.x, w = t >> 6, l = t & 63;
    const int bid = ((int)blockIdx.x & 7) * (nwg >> 3) + ((int)blockIdx.x >> 3);
    const int bh = bid >> 3, q0 = (bid & 7) * 128;
    const int bz = bh >> 3, h = bh & 7;
    const int lq = l & 15, lg = l >> 4;
    const float* kb = (kbias != nullptr && bz >= 4) ? (kbias + (size_t)(bz - 4) * L) : nullptr;

    bf16x8 qa[2][2];
#pragma unroll
    for (int i = 0; i < 2; ++i) {
        const u16* qp = Qp + ((size_t)bh * L + q0 + w * 32 + i * 16 + lq) * 64 + lg * 8;
        qa[i][0] = ld_frag(qp);
        qa[i][1] = ld_frag(qp + 32);
    }

    const int r0 = w * 16 + (l >> 3), r1 = r0 + 8, c = l & 7;
    const u16* Ksrc0 = Kp + (size_t)bh * L * 64 + (size_t)r0 * 64 + ((c ^ (r0 & 7)) * 8);
    const u16* Ksrc1 = Kp + (size_t)bh * L * 64 + (size_t)r1 * 64 + ((c ^ (r1 & 7)) * 8);
    const u16* Vsrc0 = Vtp + (size_t)bh * 64 * L + (size_t)r0 * L + ((c ^ (r0 & 7)) * 8);
    const u16* Vsrc1 = Vtp + (size_t)bh * 64 * L + (size_t)r1 * L + ((c ^ (r1 & 7)) * 8);

    auto stage = [&](int k0, int buf) {
        gl_lds16(Ksrc0 + (size_t)k0 * 64, &Kl[buf][(w * 16) * 64]);
        gl_lds16(Ksrc1 + (size_t)k0 * 64, &Kl[buf][(w * 16 + 8) * 64]);
        gl_lds16(Vsrc0 + k0, &Vl[buf][(w * 16) * 64]);
        gl_lds16(Vsrc1 + k0, &Vl[buf][(w * 16 + 8) * 64]);
    };

    int addrA[4][2];
#pragma unroll
    for (int f = 0; f < 4; ++f) {
        int row = f * 16 + lq;
#pragma unroll
        for (int s = 0; s < 2; ++s) addrA[f][s] = row * 64 + (((s * 4 + lg) ^ (row & 7)) * 8);
    }
    // P: write addr (b64, this lane's 4 k-contiguous values) per (i,f); read addr per (i,s)
    int pwr[2][4], paddr[2][2];
#pragma unroll
    for (int i = 0; i < 2; ++i) {
        const int q = w * 32 + i * 16 + lq;
#pragma unroll
        for (int f = 0; f < 4; ++f) {
            const int chunk = f * 2 + (lg >> 1);
            pwr[i][f] = q * 64 + ((chunk ^ (lq & 7)) * 8) + (lg & 1) * 4;
        }
#pragma unroll
        for (int s = 0; s < 2; ++s) paddr[i][s] = q * 64 + (((s * 4 + lg) ^ (lq & 7)) * 8);
    }

    f32x4 oacc[2][4] = {};
    float lsum[2] = {0.f, 0.f};

    stage(0, 0);
    for (int kt = 0; kt < 16; ++kt) {
        const int cur = kt & 1;
        __syncthreads();
        if (kt + 1 < 16) stage((kt + 1) * 64, cur ^ 1);

        // S^T = K Q^T : col = q (lq), row = key (lg*4+r), f indexes key subtiles
        f32x4 sc[2][4];
#pragma unroll
        for (int f = 0; f < 4; ++f) {
            bf16x8 k0 = ld_frag(&Kl[cur][addrA[f][0]]);
            bf16x8 k1 = ld_frag(&Kl[cur][addrA[f][1]]);
#pragma unroll
            for (int i = 0; i < 2; ++i) {
                f32x4 a = {};
                a = __builtin_amdgcn_mfma_f32_16x16x32_bf16(k0, qa[i][0], a, 0, 0, 0);
                a = __builtin_amdgcn_mfma_f32_16x16x32_bf16(k1, qa[i][1], a, 0, 0, 0);
                sc[i][f] = a;
            }
        }
        // softmax: lane owns q=lq, keys f*16+lg*4+r ; bias via aligned float4
#pragma unroll
        for (int f = 0; f < 4; ++f) {
            float4 bv4;
            if (kb) bv4 = *reinterpret_cast<const float4*>(kb + kt * 64 + f * 16 + lg * 4);
            else { bv4.x = 0.f; bv4.y = 0.f; bv4.z = 0.f; bv4.w = 0.f; }
#pragma unroll
            for (int i = 0; i < 2; ++i) {
                float p0 = __expf(sc[i][f][0] + bv4.x);
                float p1 = __expf(sc[i][f][1] + bv4.y);
                float p2 = __expf(sc[i][f][2] + bv4.z);
                float p3 = __expf(sc[i][f][3] + bv4.w);
                lsum[i] += (p0 + p1) + (p2 + p3);
                uint2 pk;
                pk.x = (unsigned)f2b(p0) | ((unsigned)f2b(p1) << 16);
                pk.y = (unsigned)f2b(p2) | ((unsigned)f2b(p3) << 16);
                *reinterpret_cast<uint2*>(&Pl[pwr[i][f]]) = pk;
            }
        }
        bf16x8 pa[2][2];
#pragma unroll
        for (int i = 0; i < 2; ++i) {
            pa[i][0] = ld_frag(&Pl[paddr[i][0]]);
            pa[i][1] = ld_frag(&Pl[paddr[i][1]]);
        }
#pragma unroll
        for (int db = 0; db < 4; ++db) {
            bf16x8 v0 = ld_frag(&Vl[cur][addrA[db][0]]);
            bf16x8 v1 = ld_frag(&Vl[cur][addrA[db][1]]);
#pragma unroll
            for (int i = 0; i < 2; ++i) {
                oacc[i][db] = __builtin_amdgcn_mfma_f32_16x16x32_bf16(pa[i][0], v0, oacc[i][db], 0, 0, 0);
                oacc[i][db] = __builtin_amdgcn_mfma_f32_16x16x32_bf16(pa[i][1], v1, oacc[i][db], 0, 0, 0);
            }
        }
    }
    // denominator: sum across the 4 lane-groups holding the same q (xor 16, 32)
#pragma unroll
    for (int i = 0; i < 2; ++i) {
        float v = lsum[i];
        v += __shfl_xor(v, 16, 64);
        v += __shfl_xor(v, 32, 64);
        lsum[i] = v;
    }
    // epilogue: oacc row q = w*32+i*16+lg*4+r ; its denom lives in lane (lg*4+r)
#pragma unroll
    for (int i = 0; i < 2; ++i) {
        float inv[4];
#pragma unroll
        for (int r = 0; r < 4; ++r) {
            float den = __shfl(lsum[i], lg * 4 + r, 64);
            inv[r] = (den > 0.f) ? 1.f / den : 0.f;
        }
#pragma unroll
        for (int db = 0; db < 4; ++db) {
#pragma unroll
            for (int r = 0; r < 4; ++r) {
                O[((size_t)bz * L + q0 + w * 32 + i * 16 + lg * 4 + r) * 512 + h * 64 + db * 16 + lq] =
                    f2b(oacc[i][db][r] * inv[r]);
            }
        }
    }
}

// ---------- host ----------
extern "C" void kernel_launch(void* const* d_in, const int* in_sizes, int n_in,
                              void* d_out, int out_size, void* d_ws, size_t ws_size,
                              hipStream_t stream) {
    const int M = 4096;
    const float* LL = (const float*)d_in[0];
    const float* LH = (const float*)d_in[1];
    const float* raw_tau = (const float*)d_in[2];
    auto F = [&](int i) { return (const float*)d_in[i]; };
    const int BIG = 1 << 28;

    char* p = (char*)d_ws;
    auto alloc = [&](size_t bytes) { void* r = (void*)p; p += (bytes + 255) & ~(size_t)255; return r; };
    const size_t MDf = (size_t)M * 512 * 4, MDb = (size_t)M * 512 * 2;
    float* ll_s_f = (float*)alloc(MDf);
    float* lh_s_f = (float*)alloc(MDf);
    u16* ll_s_b = (u16*)alloc(MDb);
    u16* lh_s_b = (u16*)alloc(MDb);
    u16* Qp = (u16*)alloc(2 * MDb);
    u16* Kp = (u16*)alloc(2 * MDb);
    u16* Vt = (u16*)alloc(2 * MDb);
    u16* Cxb = (u16*)alloc(2 * MDb);
    float* ll_o_f = (float*)alloc(MDf);
    u16* ll_o_b = (u16*)alloc(MDb);
    float* lh_o_f = (float*)alloc(MDf);
    u16* lh_o_b = (u16*)alloc(MDb);
    float* cr_o_f = (float*)alloc(MDf);
    float* ln_f_ll = (float*)alloc(MDf);
    float* ln_f_lh = (float*)alloc(MDf);
    u16* ln_b = (u16*)alloc(MDb);
    u16* hb = (u16*)alloc((size_t)M * 2048 * 2);
    float* yf_ll = (float*)alloc(MDf);
    float* yf_lh = (float*)alloc(MDf);
    float* kbias = (float*)alloc(4096 * 4);
    float* bqkv_ll = (float*)alloc(1536 * 4);
    float* bqkv_lh = (float*)alloc(1536 * 4);
    float* bkv_cr = (float*)alloc(1024 * 4);
    const size_t WDD = (size_t)262144;
    u16* wqkv_ll = (u16*)alloc(3 * WDD * 2);
    u16* wqkv_lh = (u16*)alloc(3 * WDD * 2);
    u16* wkv_cr = (u16*)alloc(2 * WDD * 2);
    u16* wq_cr = (u16*)alloc(WDD * 2);
    u16* wo_ll = (u16*)alloc(WDD * 2);
    u16* wo_lh = (u16*)alloc(WDD * 2);
    u16* wo_cr = (u16*)alloc(WDD * 2);
    u16* wm[4];
    for (int i = 0; i < 4; ++i) wm[i] = (u16*)alloc((size_t)1048576 * 2);

    const size_t SET = (size_t)4 * 8 * 1024 * 64;

    // fused prologue (conv + bias copies + transpose-in)
    PreArgs pa;
    pa.LL = LL; pa.LH = LH;
    pa.llf = ll_s_f; pa.llb = ll_s_b; pa.lhf = lh_s_f; pa.lhb = lh_s_b;
    pa.ce[0] = {F(3), wqkv_ll, (int)WDD};
    pa.ce[1] = {F(5), wqkv_ll + WDD, (int)WDD};
    pa.ce[2] = {F(7), wqkv_ll + 2 * WDD, (int)WDD};
    pa.ce[3] = {F(11), wqkv_lh, (int)WDD};
    pa.ce[4] = {F(13), wqkv_lh + WDD, (int)WDD};
    pa.ce[5] = {F(15), wqkv_lh + 2 * WDD, (int)WDD};
    pa.ce[6] = {F(19), wq_cr, (int)WDD};
    pa.ce[7] = {F(21), wkv_cr, (int)WDD};
    pa.ce[8] = {F(23), wkv_cr + WDD, (int)WDD};
    pa.ce[9] = {F(9), wo_ll, (int)WDD};
    pa.ce[10] = {F(17), wo_lh, (int)WDD};
    pa.ce[11] = {F(25), wo_cr, (int)WDD};
    pa.ce[12] = {F(27), wm[0], 1048576};
    pa.ce[13] = {F(29), wm[1], 1048576};
    pa.ce[14] = {F(31), wm[2], 1048576};
    pa.ce[15] = {F(33), wm[3], 1048576};
    pa.pe[0] = {F(4), bqkv_ll};
    pa.pe[1] = {F(6), bqkv_ll + 512};
    pa.pe[2] = {F(8), bqkv_ll + 1024};
    pa.pe[3] = {F(12), bqkv_lh};
    pa.pe[4] = {F(14), bqkv_lh + 512};
    pa.pe[5] = {F(16), bqkv_lh + 1024};
    pa.pe[6] = {F(22), bkv_cr};
    pa.pe[7] = {F(24), bkv_cr + 512};
    k_pre<<<dim3(8208), 256, 0, stream>>>(pa);
    k_mask<<<dim3(1024), 256, 0, stream>>>(lh_s_f, raw_tau, kbias);

    auto gp = [&](const u16* A, const u16* W, const float* bias, int N, int K, int nwg) {
        GP g = {};
        g.A = A; g.W = W; g.bias = bias; g.N = N; g.K = K; g.nwg = nwg;
        g.kB = BIG; g.vB = BIG;
        return g;
    };

    // qkv pair (128x128, y selects ll/lh)
    {
        GP a = gp(ll_s_b, wqkv_ll, bqkv_ll, 1536, 512, 384);
        a.kB = 512; a.vB = 1024; a.Qp = Qp; a.Kp = Kp; a.Vt = Vt;
        GP b = gp(lh_s_b, wqkv_lh, bqkv_lh, 1536, 512, 384);
        b.kB = 512; b.vB = 1024; b.Qp = Qp + SET; b.Kp = Kp + SET; b.Vt = Vt + SET;
        k_gemm<128, 128, 0, 1><<<dim3(384, 2), 256, 0, stream>>>(a, b, M);
    }
    // merged self-attention (512 blocks: 64 bh x 8 q-tiles of 128)
    k_attn<<<dim3(512), 256, 0, stream>>>(Qp, Kp, Vt, Cxb, kbias, 512);
    // wo pair
    {
        GP a = gp(Cxb, wo_ll, F(10), 512, 512, 512);
        a.Cf = ll_o_f; a.Cb = ll_o_b;
        GP b = gp(Cxb + SET, wo_lh, F(18), 512, 512, 512);
        b.Cf = lh_o_f; b.Cb = lh_o_b;
        k_gemm<64, 64, 0, 0><<<dim3(512, 2), 256, 0, stream>>>(a, b, M);
    }
    k_ln<<<dim3(1024), 256, 0, stream>>>(lh_s_f, lh_o_f, nullptr, F(37), F(38), ln_f_lh, ln_b);
    // mlp_lh_up
    {
        GP a = gp(ln_b, wm[2], F(32), 2048, 512, 512);
        a.Cb = hb;
        k_gemm<128, 128, 1, 0><<<dim3(512, 1), 256, 0, stream>>>(a, a, M);
    }
    // crQ + crKV pair
    {
        GP a = gp(ll_o_b, wq_cr, F(20), 512, 512, 512);
        a.Qp = Qp;
        GP b = gp(lh_o_b, wkv_cr, bkv_cr, 1024, 512, 1024);
        b.kB = 0; b.vB = 512; b.Kp = Kp; b.Vt = Vt;
        k_gemm<64, 64, 0, 1><<<dim3(1024, 2), 256, 0, stream>>>(a, b, M);
    }
    // cross attention (256 blocks)
    k_attn<<<dim3(256), 256, 0, stream>>>(Qp, Kp, Vt, Cxb, nullptr, 256);
    // wo_cr + mlp_lh_down pair
    {
        GP a = gp(Cxb, wo_cr, F(26), 512, 512, 512);
        a.Cf = cr_o_f;
        GP b = gp(hb, wm[3], F(34), 512, 2048, 512);
        b.Cf = yf_lh; b.res = ln_f_lh;
        k_gemm<64, 64, 0, 0><<<dim3(512, 2), 256, 0, stream>>>(a, b, M);
    }
    k_ln<<<dim3(1024), 256, 0, stream>>>(ll_s_f, ll_o_f, cr_o_f, F(35), F(36), ln_f_ll, ln_b);
    // mlp_ll_up
    {
        GP a = gp(ln_b, wm[0], F(28), 2048, 512, 512);
        a.Cb = hb;
        k_gemm<128, 128, 1, 0><<<dim3(512, 1), 256, 0, stream>>>(a, a, M);
    }
    // mlp_ll_down
    {
        GP a = gp(hb, wm[1], F(30), 512, 2048, 512);
        a.Cf = yf_ll; a.res = ln_f_ll;
        k_gemm<64, 64, 0, 0><<<dim3(512, 1), 256, 0, stream>>>(a, a, M);
    }
    k_tout<<<dim3(32, 16, 8), dim3(32, 8), 0, stream>>>(yf_ll, yf_lh, (float*)d_out);
}